// Round 1
// baseline (2286.822 us; speedup 1.0000x reference)
//
#include <hip/hip_runtime.h>
#include <math.h>

#define B_SZ   2
#define LSEQ   1024
#define DMODEL 1024
#define DINNER 2048
#define DSTATE 16
#define NTOK   (B_SZ * LSEQ)          // 2048 tokens
#define NSSM   (DINNER + 2 * DSTATE)  // 2080

// ---------------- RMSNorm: one block per token row ----------------
__global__ __launch_bounds__(256) void rmsnorm_kernel(
    const float* __restrict__ x, const float* __restrict__ w,
    float* __restrict__ xn) {
  int row = blockIdx.x;
  const float* xrow = x + (size_t)row * DMODEL;
  float v[4];
  float ss = 0.f;
#pragma unroll
  for (int i = 0; i < 4; i++) {
    v[i] = xrow[threadIdx.x + 256 * i];
    ss += v[i] * v[i];
  }
  __shared__ float wsum[4];
  int lane = threadIdx.x & 63, wid = threadIdx.x >> 6;
#pragma unroll
  for (int off = 1; off < 64; off <<= 1) ss += __shfl_xor(ss, off);
  if (lane == 0) wsum[wid] = ss;
  __syncthreads();
  float tot = wsum[0] + wsum[1] + wsum[2] + wsum[3];
  float scale = rsqrtf(tot / (float)DMODEL + 1e-5f);
#pragma unroll
  for (int i = 0; i < 4; i++) {
    int j = threadIdx.x + 256 * i;
    xn[(size_t)row * DMODEL + j] = v[i] * scale * w[j];
  }
}

// ---------------- Generic guarded fp32 GEMM: C[M,N] = A[M,K] @ B[K,N] (+addend) ----------------
// 64x64 tile, BK=16, 256 threads, 4x4 micro-tile per thread.
__global__ __launch_bounds__(256) void gemm64(
    const float* __restrict__ A, int lda,
    const float* __restrict__ Bm, int ldb,
    float* __restrict__ C, int ldc,
    const float* __restrict__ addend,  // nullable, layout [M, ldc]
    int M, int N, int K) {
  __shared__ float As[16][68];  // transposed A tile, +4 pad keeps float4 align
  __shared__ float Bs[16][68];
  const int bm = blockIdx.y * 64, bn = blockIdx.x * 64;
  const int tid = threadIdx.x;
  const int tx = tid & 15, ty = tid >> 4;
  const int a_m = tid >> 2;           // 0..63
  const int a_k4 = (tid & 3) << 2;    // 0,4,8,12
  const int b_k = tid >> 4;           // 0..15
  const int b_n4 = (tid & 15) << 2;   // 0..60
  const bool a_ok = (bm + a_m) < M;
  const bool b_ok = (bn + b_n4) < N;  // N multiple of 4 -> float4 all-or-none
  float acc[4][4] = {};
  for (int k0 = 0; k0 < K; k0 += 16) {
    float4 av = a_ok ? *(const float4*)(A + (size_t)(bm + a_m) * lda + k0 + a_k4)
                     : make_float4(0.f, 0.f, 0.f, 0.f);
    float4 bv = b_ok ? *(const float4*)(Bm + (size_t)(k0 + b_k) * ldb + bn + b_n4)
                     : make_float4(0.f, 0.f, 0.f, 0.f);
    As[a_k4 + 0][a_m] = av.x;
    As[a_k4 + 1][a_m] = av.y;
    As[a_k4 + 2][a_m] = av.z;
    As[a_k4 + 3][a_m] = av.w;
    *(float4*)&Bs[b_k][b_n4] = bv;
    __syncthreads();
#pragma unroll
    for (int kk = 0; kk < 16; kk++) {
      float4 a4 = *(const float4*)&As[kk][ty << 2];
      float4 b4 = *(const float4*)&Bs[kk][tx << 2];
      float aa[4] = {a4.x, a4.y, a4.z, a4.w};
      float bb[4] = {b4.x, b4.y, b4.z, b4.w};
#pragma unroll
      for (int i = 0; i < 4; i++)
#pragma unroll
        for (int j = 0; j < 4; j++) acc[i][j] = fmaf(aa[i], bb[j], acc[i][j]);
    }
    __syncthreads();
  }
#pragma unroll
  for (int i = 0; i < 4; i++) {
    int m = bm + (ty << 2) + i;
    if (m >= M) continue;
#pragma unroll
    for (int j = 0; j < 4; j++) {
      int n = bn + (tx << 2) + j;
      if (n >= N) continue;
      float r = acc[i][j];
      if (addend) r += addend[(size_t)m * ldc + n];
      C[(size_t)m * ldc + n] = r;
    }
  }
}

// ---------------- causal depthwise conv(4) + bias + silu ----------------
// xr is [NTOK, 4096]; xs part = cols [0,2048). Output xs_conv [NTOK, 2048].
__global__ __launch_bounds__(256) void conv_silu_kernel(
    const float* __restrict__ xr, const float* __restrict__ cw,
    const float* __restrict__ cb, float* __restrict__ xs) {
  int gid = blockIdx.x * 256 + threadIdx.x;  // [0, NTOK*DINNER)
  int c = gid & (DINNER - 1);
  int t = gid >> 11;         // token index b*L + l
  int l = t & (LSEQ - 1);
  float w0 = cw[c * 4 + 0], w1 = cw[c * 4 + 1], w2 = cw[c * 4 + 2], w3 = cw[c * 4 + 3];
  const float* col = xr + (size_t)t * 4096 + c;
  float acc = cb[c] + w3 * col[0];
  if (l >= 1) acc += w2 * col[-4096];
  if (l >= 2) acc += w1 * col[-2 * 4096];
  if (l >= 3) acc += w0 * col[-3 * 4096];
  xs[gid] = acc / (1.f + expf(-acc));  // silu
}

// ---------------- selective scan ----------------
// One 16-lane group per (b, d) channel; lane n holds state n.
// y may alias dt_raw (element read before written within the same wave step).
__global__ __launch_bounds__(256) void scan_kernel(
    const float* dt_raw, const float* __restrict__ xs,
    const float* __restrict__ ssm, const float* __restrict__ xr,
    const float* __restrict__ A_log, float* y) {
  int wave = blockIdx.x * 4 + (threadIdx.x >> 6);  // 0..1023
  int lane = threadIdx.x & 63;
  int b = wave >> 9;          // / (DINNER/4)
  int dgroup = wave & 511;
  int sub = lane >> 4, n = lane & 15;
  int d = dgroup * 4 + sub;
  float a_coef = -expf(A_log[d * DSTATE + n]);
  float h = 0.f;
  size_t tok0 = (size_t)b * LSEQ;
  for (int l = 0; l < LSEQ; l++) {
    size_t t = tok0 + l;
    float dtr = dt_raw[t * DINNER + d];
    float dt = (dtr > 20.f) ? dtr : log1pf(expf(dtr));  // softplus
    float xsv = xs[t * DINNER + d];
    float Bv = ssm[t * NSSM + DINNER + n];
    float Cv = ssm[t * NSSM + DINNER + DSTATE + n];
    h = expf(a_coef * dt) * h + dt * Bv * xsv;
    float p = h * Cv;
    p += __shfl_xor(p, 1);
    p += __shfl_xor(p, 2);
    p += __shfl_xor(p, 4);
    p += __shfl_xor(p, 8);
    if (n == 0) {
      float res = xr[t * 4096 + DINNER + d];
      y[t * DINNER + d] = p * (res / (1.f + expf(-res)));  // * silu(res)
    }
  }
}

extern "C" void kernel_launch(void* const* d_in, const int* in_sizes, int n_in,
                              void* d_out, int out_size, void* d_ws, size_t ws_size,
                              hipStream_t stream) {
  const float* x      = (const float*)d_in[0];
  const float* rms_w  = (const float*)d_in[1];
  const float* W_in   = (const float*)d_in[2];
  const float* conv_w = (const float*)d_in[3];
  const float* conv_b = (const float*)d_in[4];
  const float* W_x    = (const float*)d_in[5];
  const float* W_dt   = (const float*)d_in[6];
  const float* A_log  = (const float*)d_in[7];
  const float* W_out  = (const float*)d_in[8];
  float* out = (float*)d_out;

  // workspace layout (floats): 92.5 MB total
  float* ws  = (float*)d_ws;
  float* xn  = ws;                               // [2048,1024]
  float* xr  = xn + (size_t)NTOK * DMODEL;       // [2048,4096]
  float* xs  = xr + (size_t)NTOK * 4096;         // [2048,2048]
  float* ssm = xs + (size_t)NTOK * DINNER;       // [2048,2080]
  float* dtb = ssm + (size_t)NTOK * NSSM;        // [2048,2048], reused as y

  rmsnorm_kernel<<<NTOK, 256, 0, stream>>>(x, rms_w, xn);
  // xr = xn @ W_in
  gemm64<<<dim3(4096 / 64, NTOK / 64), 256, 0, stream>>>(
      xn, DMODEL, W_in, 4096, xr, 4096, nullptr, NTOK, 4096, DMODEL);
  conv_silu_kernel<<<(NTOK * DINNER) / 256, 256, 0, stream>>>(xr, conv_w, conv_b, xs);
  // ssm = xs @ W_x  (N=2080, guarded tail tile)
  gemm64<<<dim3((NSSM + 63) / 64, NTOK / 64), 256, 0, stream>>>(
      xs, DINNER, W_x, NSSM, ssm, NSSM, nullptr, NTOK, NSSM, DINNER);
  // dtb = dt_in @ W_dt  (dt_in = ssm cols [0,2048), lda=2080)
  gemm64<<<dim3(DINNER / 64, NTOK / 64), 256, 0, stream>>>(
      ssm, NSSM, W_dt, DINNER, dtb, DINNER, nullptr, NTOK, DINNER, DINNER);
  // scan: reads dtb/xs/ssm/xr, writes y over dtb
  scan_kernel<<<256, 256, 0, stream>>>(dtb, xs, ssm, xr, A_log, dtb);
  // out = y @ W_out + x
  gemm64<<<dim3(DMODEL / 64, NTOK / 64), 256, 0, stream>>>(
      dtb, DINNER, W_out, DMODEL, out, DMODEL, x, NTOK, DMODEL, DINNER);
}

// Round 2
// 1523.653 us; speedup vs baseline: 1.5009x; 1.5009x over previous
//
#include <hip/hip_runtime.h>
#include <math.h>

#define B_SZ   2
#define LSEQ   1024
#define DMODEL 1024
#define DINNER 2048
#define DSTATE 16
#define NTOK   (B_SZ * LSEQ)          // 2048 tokens
#define NSSM   (DINNER + 2 * DSTATE)  // 2080
#define CL     64                     // scan chunk length
#define NCH    (LSEQ / CL)            // 16 chunks
#define NC     (B_SZ * DINNER)        // 4096 channels

// ---------------- RMSNorm: one block per token row ----------------
__global__ __launch_bounds__(256) void rmsnorm_kernel(
    const float* __restrict__ x, const float* __restrict__ w,
    float* __restrict__ xn) {
  int row = blockIdx.x;
  const float* xrow = x + (size_t)row * DMODEL;
  float v[4];
  float ss = 0.f;
#pragma unroll
  for (int i = 0; i < 4; i++) {
    v[i] = xrow[threadIdx.x + 256 * i];
    ss += v[i] * v[i];
  }
  __shared__ float wsum[4];
  int lane = threadIdx.x & 63, wid = threadIdx.x >> 6;
#pragma unroll
  for (int off = 1; off < 64; off <<= 1) ss += __shfl_xor(ss, off);
  if (lane == 0) wsum[wid] = ss;
  __syncthreads();
  float tot = wsum[0] + wsum[1] + wsum[2] + wsum[3];
  float scale = rsqrtf(tot / (float)DMODEL + 1e-5f);
#pragma unroll
  for (int i = 0; i < 4; i++) {
    int j = threadIdx.x + 256 * i;
    xn[(size_t)row * DMODEL + j] = v[i] * scale * w[j];
  }
}

// ---------------- Generic guarded fp32 GEMM: C[M,N] = A[M,K] @ B[K,N] (+addend) ----------------
__global__ __launch_bounds__(256) void gemm64(
    const float* __restrict__ A, int lda,
    const float* __restrict__ Bm, int ldb,
    float* __restrict__ C, int ldc,
    const float* __restrict__ addend,  // nullable, layout [M, ldc]
    int M, int N, int K) {
  __shared__ float As[16][68];
  __shared__ float Bs[16][68];
  const int bm = blockIdx.y * 64, bn = blockIdx.x * 64;
  const int tid = threadIdx.x;
  const int tx = tid & 15, ty = tid >> 4;
  const int a_m = tid >> 2;
  const int a_k4 = (tid & 3) << 2;
  const int b_k = tid >> 4;
  const int b_n4 = (tid & 15) << 2;
  const bool a_ok = (bm + a_m) < M;
  const bool b_ok = (bn + b_n4) < N;
  float acc[4][4] = {};
  for (int k0 = 0; k0 < K; k0 += 16) {
    float4 av = a_ok ? *(const float4*)(A + (size_t)(bm + a_m) * lda + k0 + a_k4)
                     : make_float4(0.f, 0.f, 0.f, 0.f);
    float4 bv = b_ok ? *(const float4*)(Bm + (size_t)(k0 + b_k) * ldb + bn + b_n4)
                     : make_float4(0.f, 0.f, 0.f, 0.f);
    As[a_k4 + 0][a_m] = av.x;
    As[a_k4 + 1][a_m] = av.y;
    As[a_k4 + 2][a_m] = av.z;
    As[a_k4 + 3][a_m] = av.w;
    *(float4*)&Bs[b_k][b_n4] = bv;
    __syncthreads();
#pragma unroll
    for (int kk = 0; kk < 16; kk++) {
      float4 a4 = *(const float4*)&As[kk][ty << 2];
      float4 b4 = *(const float4*)&Bs[kk][tx << 2];
      float aa[4] = {a4.x, a4.y, a4.z, a4.w};
      float bb[4] = {b4.x, b4.y, b4.z, b4.w};
#pragma unroll
      for (int i = 0; i < 4; i++)
#pragma unroll
        for (int j = 0; j < 4; j++) acc[i][j] = fmaf(aa[i], bb[j], acc[i][j]);
    }
    __syncthreads();
  }
#pragma unroll
  for (int i = 0; i < 4; i++) {
    int m = bm + (ty << 2) + i;
    if (m >= M) continue;
#pragma unroll
    for (int j = 0; j < 4; j++) {
      int n = bn + (tx << 2) + j;
      if (n >= N) continue;
      float r = acc[i][j];
      if (addend) r += addend[(size_t)m * ldc + n];
      C[(size_t)m * ldc + n] = r;
    }
  }
}

// ---------------- causal depthwise conv(4) + bias + silu ----------------
__global__ __launch_bounds__(256) void conv_silu_kernel(
    const float* __restrict__ xr, const float* __restrict__ cw,
    const float* __restrict__ cb, float* __restrict__ xs) {
  int gid = blockIdx.x * 256 + threadIdx.x;
  int c = gid & (DINNER - 1);
  int t = gid >> 11;
  int l = t & (LSEQ - 1);
  float w0 = cw[c * 4 + 0], w1 = cw[c * 4 + 1], w2 = cw[c * 4 + 2], w3 = cw[c * 4 + 3];
  const float* col = xr + (size_t)t * 4096 + c;
  float acc = cb[c] + w3 * col[0];
  if (l >= 1) acc += w2 * col[-4096];
  if (l >= 2) acc += w1 * col[-2 * 4096];
  if (l >= 3) acc += w0 * col[-3 * 4096];
  xs[gid] = acc / (1.f + expf(-acc));
}

// ---------------- chunked selective scan ----------------
// Phase 1: per (channel, chunk): local scan from h=0, record final h and sum(dt).
// Subgroup = 16 consecutive lanes (lane n = state n); block = (b, chunk, 16 d's).
__global__ __launch_bounds__(256) void scan_chunk1(
    const float* __restrict__ dt_raw, const float* __restrict__ xs,
    const float* __restrict__ ssm, const float* __restrict__ A_log,
    float* __restrict__ Bc, float* __restrict__ S) {
  int blk = blockIdx.x;                 // [0, B_SZ*NCH*128)
  int b = blk >> 11;                    // / (NCH*128)
  int rem = blk & 2047;
  int ch = rem >> 7;
  int dblk = rem & 127;
  int sub = threadIdx.x >> 4, n = threadIdx.x & 15;
  int d = dblk * 16 + sub;
  int c = b * DINNER + d;
  float a_coef = -expf(A_log[d * DSTATE + n]);
  float h = 0.f, Ssum = 0.f;
  size_t t = (size_t)b * LSEQ + (size_t)ch * CL;
  for (int l = 0; l < CL; l++, t++) {
    float dtr = dt_raw[t * DINNER + d];
    float dt = (dtr > 20.f) ? dtr : log1pf(expf(dtr));
    Ssum += dt;
    float xsv = xs[t * DINNER + d];
    float Bv = ssm[t * NSSM + DINNER + n];
    h = expf(a_coef * dt) * h + dt * Bv * xsv;
  }
  Bc[(size_t)c * (NCH * DSTATE) + ch * DSTATE + n] = h;
  if (n == 0) S[c * NCH + ch] = Ssum;
}

// Phase 2: sequential combine over chunks; converts Bc (chunk local sums)
// into h_in per chunk IN-PLACE (read Bc[ch] before overwriting with h_in).
__global__ __launch_bounds__(256) void scan_combine(
    const float* __restrict__ A_log, const float* __restrict__ S,
    float* BcHin) {
  int gid = blockIdx.x * 256 + threadIdx.x;  // [0, NC*DSTATE)
  int c = gid >> 4, n = gid & 15;
  int d = c & (DINNER - 1);
  float a_coef = -expf(A_log[d * DSTATE + n]);
  float h = 0.f;
  size_t base = (size_t)c * (NCH * DSTATE) + n;
  for (int ch = 0; ch < NCH; ch++) {
    float bc = BcHin[base + (size_t)ch * DSTATE];
    float a = expf(a_coef * S[c * NCH + ch]);
    BcHin[base + (size_t)ch * DSTATE] = h;  // h_in for this chunk
    h = a * h + bc;
  }
}

// Phase 3: rerun each chunk seeded with h_in; emit y = (h·C) * silu(res).
// y aliases dt_raw: each element is read (all 16 lanes) before lane 0 writes it.
__global__ __launch_bounds__(256) void scan_chunk2(
    const float* dt_raw, const float* __restrict__ xs,
    const float* __restrict__ ssm, const float* __restrict__ xr,
    const float* __restrict__ A_log, const float* __restrict__ hin,
    float* y) {
  int blk = blockIdx.x;
  int b = blk >> 11;
  int rem = blk & 2047;
  int ch = rem >> 7;
  int dblk = rem & 127;
  int sub = threadIdx.x >> 4, n = threadIdx.x & 15;
  int d = dblk * 16 + sub;
  int c = b * DINNER + d;
  float a_coef = -expf(A_log[d * DSTATE + n]);
  float h = hin[(size_t)c * (NCH * DSTATE) + ch * DSTATE + n];
  size_t t = (size_t)b * LSEQ + (size_t)ch * CL;
  for (int l = 0; l < CL; l++, t++) {
    float dtr = dt_raw[t * DINNER + d];
    float dt = (dtr > 20.f) ? dtr : log1pf(expf(dtr));
    float xsv = xs[t * DINNER + d];
    float Bv = ssm[t * NSSM + DINNER + n];
    float Cv = ssm[t * NSSM + DINNER + DSTATE + n];
    h = expf(a_coef * dt) * h + dt * Bv * xsv;
    float p = h * Cv;
    p += __shfl_xor(p, 1);
    p += __shfl_xor(p, 2);
    p += __shfl_xor(p, 4);
    p += __shfl_xor(p, 8);
    if (n == 0) {
      float res = xr[t * 4096 + DINNER + d];
      y[t * DINNER + d] = p * (res / (1.f + expf(-res)));
    }
  }
}

extern "C" void kernel_launch(void* const* d_in, const int* in_sizes, int n_in,
                              void* d_out, int out_size, void* d_ws, size_t ws_size,
                              hipStream_t stream) {
  const float* x      = (const float*)d_in[0];
  const float* rms_w  = (const float*)d_in[1];
  const float* W_in   = (const float*)d_in[2];
  const float* conv_w = (const float*)d_in[3];
  const float* conv_b = (const float*)d_in[4];
  const float* W_x    = (const float*)d_in[5];
  const float* W_dt   = (const float*)d_in[6];
  const float* A_log  = (const float*)d_in[7];
  const float* W_out  = (const float*)d_in[8];
  float* out = (float*)d_out;

  // workspace layout (floats)
  float* ws  = (float*)d_ws;
  float* xn  = ws;                               // [2048,1024] — free after GEMM1
  float* xr  = xn + (size_t)NTOK * DMODEL;       // [2048,4096]
  float* xs  = xr + (size_t)NTOK * 4096;         // [2048,2048]
  float* ssm = xs + (size_t)NTOK * DINNER;       // [2048,2080]
  float* dtb = ssm + (size_t)NTOK * NSSM;        // [2048,2048], reused as y
  // scan scratch reuses the xn region (xn dead after GEMM1): 4.25 MB < 8 MB
  float* Bc  = xn;                               // [NC, NCH, DSTATE] = 4 MB
  float* S   = Bc + (size_t)NC * NCH * DSTATE;   // [NC, NCH] = 0.25 MB

  rmsnorm_kernel<<<NTOK, 256, 0, stream>>>(x, rms_w, xn);
  gemm64<<<dim3(4096 / 64, NTOK / 64), 256, 0, stream>>>(
      xn, DMODEL, W_in, 4096, xr, 4096, nullptr, NTOK, 4096, DMODEL);
  conv_silu_kernel<<<(NTOK * DINNER) / 256, 256, 0, stream>>>(xr, conv_w, conv_b, xs);
  gemm64<<<dim3((NSSM + 63) / 64, NTOK / 64), 256, 0, stream>>>(
      xs, DINNER, W_x, NSSM, ssm, NSSM, nullptr, NTOK, NSSM, DINNER);
  gemm64<<<dim3(DINNER / 64, NTOK / 64), 256, 0, stream>>>(
      ssm, NSSM, W_dt, DINNER, dtb, DINNER, nullptr, NTOK, DINNER, DINNER);
  // chunked scan
  scan_chunk1<<<B_SZ * NCH * 128, 256, 0, stream>>>(dtb, xs, ssm, A_log, Bc, S);
  scan_combine<<<(NC * DSTATE) / 256, 256, 0, stream>>>(A_log, S, Bc);
  scan_chunk2<<<B_SZ * NCH * 128, 256, 0, stream>>>(dtb, xs, ssm, xr, A_log, Bc, dtb);
  gemm64<<<dim3(DMODEL / 64, NTOK / 64), 256, 0, stream>>>(
      dtb, DINNER, W_out, DMODEL, out, DMODEL, x, NTOK, DMODEL, DINNER);
}

// Round 3
// 1111.117 us; speedup vs baseline: 2.0581x; 1.3713x over previous
//
#include <hip/hip_runtime.h>
#include <math.h>

#define B_SZ   2
#define LSEQ   1024
#define DMODEL 1024
#define DINNER 2048
#define DSTATE 16
#define NTOK   (B_SZ * LSEQ)          // 2048 tokens
#define NSSM   (DINNER + 2 * DSTATE)  // 2080
#define CL     32                     // scan chunk length
#define NCH    (LSEQ / CL)            // 32 chunks
#define NC     (B_SZ * DINNER)        // 4096 channels

__device__ __forceinline__ float softplus_f(float x) {
  return (x > 20.f) ? x : __logf(1.f + __expf(x));
}
__device__ __forceinline__ float silu_f(float x) {
  return x / (1.f + __expf(-x));
}

// ---------------- RMSNorm: one block per token row ----------------
__global__ __launch_bounds__(256) void rmsnorm_kernel(
    const float* __restrict__ x, const float* __restrict__ w,
    float* __restrict__ xn) {
  int row = blockIdx.x;
  const float* xrow = x + (size_t)row * DMODEL;
  float v[4];
  float ss = 0.f;
#pragma unroll
  for (int i = 0; i < 4; i++) {
    v[i] = xrow[threadIdx.x + 256 * i];
    ss += v[i] * v[i];
  }
  __shared__ float wsum[4];
  int lane = threadIdx.x & 63, wid = threadIdx.x >> 6;
#pragma unroll
  for (int off = 1; off < 64; off <<= 1) ss += __shfl_xor(ss, off);
  if (lane == 0) wsum[wid] = ss;
  __syncthreads();
  float tot = wsum[0] + wsum[1] + wsum[2] + wsum[3];
  float scale = rsqrtf(tot / (float)DMODEL + 1e-5f);
#pragma unroll
  for (int i = 0; i < 4; i++) {
    int j = threadIdx.x + 256 * i;
    xn[(size_t)row * DMODEL + j] = v[i] * scale * w[j];
  }
}

// ---------------- Generic guarded fp32 GEMM ----------------
// C[M,N] = A[M,K]@B[K,N]; epilogue: optional addend, optional softplus.
__global__ __launch_bounds__(256) void gemm64(
    const float* __restrict__ A, int lda,
    const float* __restrict__ Bm, int ldb,
    float* __restrict__ C, int ldc,
    const float* __restrict__ addend,  // nullable, layout [M, ldc]
    int M, int N, int K, int do_softplus) {
  __shared__ float As[16][68];
  __shared__ float Bs[16][68];
  const int bm = blockIdx.y * 64, bn = blockIdx.x * 64;
  const int tid = threadIdx.x;
  const int tx = tid & 15, ty = tid >> 4;
  const int a_m = tid >> 2;
  const int a_k4 = (tid & 3) << 2;
  const int b_k = tid >> 4;
  const int b_n4 = (tid & 15) << 2;
  const bool a_ok = (bm + a_m) < M;
  const bool b_ok = (bn + b_n4) < N;
  float acc[4][4] = {};
  for (int k0 = 0; k0 < K; k0 += 16) {
    float4 av = a_ok ? *(const float4*)(A + (size_t)(bm + a_m) * lda + k0 + a_k4)
                     : make_float4(0.f, 0.f, 0.f, 0.f);
    float4 bv = b_ok ? *(const float4*)(Bm + (size_t)(k0 + b_k) * ldb + bn + b_n4)
                     : make_float4(0.f, 0.f, 0.f, 0.f);
    As[a_k4 + 0][a_m] = av.x;
    As[a_k4 + 1][a_m] = av.y;
    As[a_k4 + 2][a_m] = av.z;
    As[a_k4 + 3][a_m] = av.w;
    *(float4*)&Bs[b_k][b_n4] = bv;
    __syncthreads();
#pragma unroll
    for (int kk = 0; kk < 16; kk++) {
      float4 a4 = *(const float4*)&As[kk][ty << 2];
      float4 b4 = *(const float4*)&Bs[kk][tx << 2];
      float aa[4] = {a4.x, a4.y, a4.z, a4.w};
      float bb[4] = {b4.x, b4.y, b4.z, b4.w};
#pragma unroll
      for (int i = 0; i < 4; i++)
#pragma unroll
        for (int j = 0; j < 4; j++) acc[i][j] = fmaf(aa[i], bb[j], acc[i][j]);
    }
    __syncthreads();
  }
#pragma unroll
  for (int i = 0; i < 4; i++) {
    int m = bm + (ty << 2) + i;
    if (m >= M) continue;
#pragma unroll
    for (int j = 0; j < 4; j++) {
      int n = bn + (tx << 2) + j;
      if (n >= N) continue;
      float r = acc[i][j];
      if (addend) r += addend[(size_t)m * ldc + n];
      if (do_softplus) r = softplus_f(r);
      C[(size_t)m * ldc + n] = r;
    }
  }
}

// ---------------- causal depthwise conv(4) + bias + silu ----------------
__global__ __launch_bounds__(256) void conv_silu_kernel(
    const float* __restrict__ xr, const float* __restrict__ cw,
    const float* __restrict__ cb, float* __restrict__ xs) {
  int gid = blockIdx.x * 256 + threadIdx.x;
  int c = gid & (DINNER - 1);
  int t = gid >> 11;
  int l = t & (LSEQ - 1);
  float w0 = cw[c * 4 + 0], w1 = cw[c * 4 + 1], w2 = cw[c * 4 + 2], w3 = cw[c * 4 + 3];
  const float* col = xr + (size_t)t * 4096 + c;
  float acc = cb[c] + w3 * col[0];
  if (l >= 1) acc += w2 * col[-4096];
  if (l >= 2) acc += w1 * col[-2 * 4096];
  if (l >= 3) acc += w0 * col[-3 * 4096];
  xs[gid] = silu_f(acc);
}

// ---------------- chunked selective scan, h[16] per thread ----------------
// Phase 1: per (channel, chunk): local scan from h=0 → chunk sum h, and sum(dt).
// One thread per channel; 16 states in registers. dt is PRE-softplussed.
__global__ __launch_bounds__(256) void scan_chunk1(
    const float* __restrict__ dt, const float* __restrict__ xs,
    const float* __restrict__ ssm, const float* __restrict__ A_log,
    float* __restrict__ Bc, float* __restrict__ S) {
  int blk = blockIdx.x;              // [0, B_SZ*NCH*8)
  int b = blk >> 8;                  // / (NCH*8)
  int rem = blk & 255;
  int ch = rem >> 3;
  int dblk = rem & 7;
  int d = dblk * 256 + threadIdx.x;
  int c = b * DINNER + d;
  float a[DSTATE];
#pragma unroll
  for (int i = 0; i < 4; i++) {
    float4 v = *(const float4*)(A_log + (size_t)d * DSTATE + 4 * i);
    a[4 * i + 0] = -__expf(v.x);
    a[4 * i + 1] = -__expf(v.y);
    a[4 * i + 2] = -__expf(v.z);
    a[4 * i + 3] = -__expf(v.w);
  }
  float h[DSTATE] = {};
  float Ssum = 0.f;
  size_t t = (size_t)b * LSEQ + (size_t)ch * CL;
#pragma unroll 2
  for (int l = 0; l < CL; l++, t++) {
    float dtv = dt[t * DINNER + d];
    float dx = dtv * xs[t * DINNER + d];
    const float4* Bp = (const float4*)(ssm + t * NSSM + DINNER);
    float4 b0 = Bp[0], b1 = Bp[1], b2 = Bp[2], b3 = Bp[3];
    float bb[DSTATE] = {b0.x, b0.y, b0.z, b0.w, b1.x, b1.y, b1.z, b1.w,
                        b2.x, b2.y, b2.z, b2.w, b3.x, b3.y, b3.z, b3.w};
#pragma unroll
    for (int n = 0; n < DSTATE; n++)
      h[n] = __expf(a[n] * dtv) * h[n] + dx * bb[n];
    Ssum += dtv;
  }
  float4* out = (float4*)(Bc + ((size_t)c * NCH + ch) * DSTATE);
  out[0] = make_float4(h[0], h[1], h[2], h[3]);
  out[1] = make_float4(h[4], h[5], h[6], h[7]);
  out[2] = make_float4(h[8], h[9], h[10], h[11]);
  out[3] = make_float4(h[12], h[13], h[14], h[15]);
  S[c * NCH + ch] = Ssum;
}

// Phase 2: sequential combine over chunks; Bc (chunk sums) → h_in per chunk,
// in place (each (c,n) owned by one thread).
__global__ __launch_bounds__(256) void scan_combine(
    const float* __restrict__ A_log, const float* __restrict__ S,
    float* BcHin) {
  int gid = blockIdx.x * 256 + threadIdx.x;  // [0, NC*DSTATE)
  int c = gid >> 4, n = gid & 15;
  int d = c & (DINNER - 1);
  float a = -__expf(A_log[d * DSTATE + n]);
  float h = 0.f;
  size_t base = (size_t)c * (NCH * DSTATE) + n;
  for (int ch = 0; ch < NCH; ch++) {
    float bc = BcHin[base + (size_t)ch * DSTATE];
    float decay = __expf(a * S[c * NCH + ch]);
    BcHin[base + (size_t)ch * DSTATE] = h;
    h = decay * h + bc;
  }
}

// Phase 3: rerun chunk seeded with h_in; y = (Σ h[n]C[n]) * silu(res).
// y aliases dt: each (t,d) element is read then written by the SAME thread.
__global__ __launch_bounds__(256) void scan_chunk2(
    const float* dt, const float* __restrict__ xs,
    const float* __restrict__ ssm, const float* __restrict__ xr,
    const float* __restrict__ A_log, const float* __restrict__ hin,
    float* y) {
  int blk = blockIdx.x;
  int b = blk >> 8;
  int rem = blk & 255;
  int ch = rem >> 3;
  int dblk = rem & 7;
  int d = dblk * 256 + threadIdx.x;
  int c = b * DINNER + d;
  float a[DSTATE];
#pragma unroll
  for (int i = 0; i < 4; i++) {
    float4 v = *(const float4*)(A_log + (size_t)d * DSTATE + 4 * i);
    a[4 * i + 0] = -__expf(v.x);
    a[4 * i + 1] = -__expf(v.y);
    a[4 * i + 2] = -__expf(v.z);
    a[4 * i + 3] = -__expf(v.w);
  }
  float h[DSTATE];
  const float4* hi = (const float4*)(hin + ((size_t)c * NCH + ch) * DSTATE);
#pragma unroll
  for (int i = 0; i < 4; i++) {
    float4 v = hi[i];
    h[4 * i + 0] = v.x; h[4 * i + 1] = v.y; h[4 * i + 2] = v.z; h[4 * i + 3] = v.w;
  }
  size_t t = (size_t)b * LSEQ + (size_t)ch * CL;
#pragma unroll 2
  for (int l = 0; l < CL; l++, t++) {
    float dtv = dt[t * DINNER + d];
    float dx = dtv * xs[t * DINNER + d];
    const float4* Bp = (const float4*)(ssm + t * NSSM + DINNER);
    float4 b0 = Bp[0], b1 = Bp[1], b2 = Bp[2], b3 = Bp[3];
    const float4* Cp = (const float4*)(ssm + t * NSSM + DINNER + DSTATE);
    float4 c0 = Cp[0], c1 = Cp[1], c2 = Cp[2], c3 = Cp[3];
    float bb[DSTATE] = {b0.x, b0.y, b0.z, b0.w, b1.x, b1.y, b1.z, b1.w,
                        b2.x, b2.y, b2.z, b2.w, b3.x, b3.y, b3.z, b3.w};
    float cc[DSTATE] = {c0.x, c0.y, c0.z, c0.w, c1.x, c1.y, c1.z, c1.w,
                        c2.x, c2.y, c2.z, c2.w, c3.x, c3.y, c3.z, c3.w};
    float ysum = 0.f;
#pragma unroll
    for (int n = 0; n < DSTATE; n++) {
      h[n] = __expf(a[n] * dtv) * h[n] + dx * bb[n];
      ysum = fmaf(h[n], cc[n], ysum);
    }
    float res = xr[t * 4096 + DINNER + d];
    y[t * DINNER + d] = ysum * silu_f(res);
  }
}

extern "C" void kernel_launch(void* const* d_in, const int* in_sizes, int n_in,
                              void* d_out, int out_size, void* d_ws, size_t ws_size,
                              hipStream_t stream) {
  const float* x      = (const float*)d_in[0];
  const float* rms_w  = (const float*)d_in[1];
  const float* W_in   = (const float*)d_in[2];
  const float* conv_w = (const float*)d_in[3];
  const float* conv_b = (const float*)d_in[4];
  const float* W_x    = (const float*)d_in[5];
  const float* W_dt   = (const float*)d_in[6];
  const float* A_log  = (const float*)d_in[7];
  const float* W_out  = (const float*)d_in[8];
  float* out = (float*)d_out;

  // workspace layout (floats): 89 MB total (matches R1 footprint)
  float* ws  = (float*)d_ws;
  float* xn  = ws;                               // [2048,1024] — dead after GEMM1
  float* xr  = xn + (size_t)NTOK * DMODEL;       // [2048,4096]
  float* xs  = xr + (size_t)NTOK * 4096;         // [2048,2048]
  float* ssm = xs + (size_t)NTOK * DINNER;       // [2048,2080]
  float* dtb = ssm + (size_t)NTOK * NSSM;        // [2048,2048] dt, reused as y
  // scan scratch: Bc (8 MB) exactly fills the dead xn region;
  // S (512 KB) parks in d_out, fully overwritten by the final GEMM.
  float* Bc  = xn;                               // [NC, NCH, DSTATE] = 8 MB
  float* S   = out;                              // [NC, NCH] = 512 KB

  rmsnorm_kernel<<<NTOK, 256, 0, stream>>>(x, rms_w, xn);
  gemm64<<<dim3(4096 / 64, NTOK / 64), 256, 0, stream>>>(
      xn, DMODEL, W_in, 4096, xr, 4096, nullptr, NTOK, 4096, DMODEL, 0);
  conv_silu_kernel<<<(NTOK * DINNER) / 256, 256, 0, stream>>>(xr, conv_w, conv_b, xs);
  gemm64<<<dim3((NSSM + 63) / 64, NTOK / 64), 256, 0, stream>>>(
      xs, DINNER, W_x, NSSM, ssm, NSSM, nullptr, NTOK, NSSM, DINNER, 0);
  // dtb = softplus(dt_in @ W_dt)  — softplus fused in epilogue
  gemm64<<<dim3(DINNER / 64, NTOK / 64), 256, 0, stream>>>(
      ssm, NSSM, W_dt, DINNER, dtb, DINNER, nullptr, NTOK, DINNER, DINNER, 1);
  // chunked scan (1 thread per channel, h[16] in registers)
  scan_chunk1<<<B_SZ * NCH * 8, 256, 0, stream>>>(dtb, xs, ssm, A_log, Bc, S);
  scan_combine<<<(NC * DSTATE) / 256, 256, 0, stream>>>(A_log, S, Bc);
  scan_chunk2<<<B_SZ * NCH * 8, 256, 0, stream>>>(dtb, xs, ssm, xr, A_log, Bc, dtb);
  gemm64<<<dim3(DMODEL / 64, NTOK / 64), 256, 0, stream>>>(
      dtb, DINNER, W_out, DMODEL, out, DMODEL, x, NTOK, DMODEL, DINNER, 0);
}

// Round 4
// 390.182 us; speedup vs baseline: 5.8609x; 2.8477x over previous
//
#include <hip/hip_runtime.h>
#include <math.h>

#define B_SZ   2
#define LSEQ   1024
#define DMODEL 1024
#define DINNER 2048
#define DSTATE 16
#define NTOK   (B_SZ * LSEQ)          // 2048 tokens
#define NSSM   (DINNER + 2 * DSTATE)  // 2080
#define CL     32                     // scan chunk length
#define NCH    (LSEQ / CL)            // 32 chunks
#define NC     (B_SZ * DINNER)        // 4096 channels

typedef unsigned short ushort;
typedef __attribute__((ext_vector_type(8))) ushort ushort8;
typedef __attribute__((ext_vector_type(8))) __bf16 bf16x8;
typedef __attribute__((ext_vector_type(4))) float floatx4;

__device__ __forceinline__ float softplus_f(float x) {
  return (x > 20.f) ? x : __logf(1.f + __expf(x));
}
__device__ __forceinline__ float silu_f(float x) {
  return x / (1.f + __expf(-x));
}
__device__ __forceinline__ float bf2f(ushort u) {
  return __uint_as_float(((unsigned)u) << 16);
}
__device__ __forceinline__ ushort f2bf(float f) {  // round-to-nearest-even
  unsigned u = __float_as_uint(f);
  return (ushort)((u + 0x7FFFu + ((u >> 16) & 1u)) >> 16);
}

// ---------------- RMSNorm → bf16 ----------------
__global__ __launch_bounds__(256) void rmsnorm_kernel(
    const float* __restrict__ x, const float* __restrict__ w,
    ushort* __restrict__ xn) {
  int row = blockIdx.x;
  const float* xrow = x + (size_t)row * DMODEL;
  float v[4];
  float ss = 0.f;
#pragma unroll
  for (int i = 0; i < 4; i++) {
    v[i] = xrow[threadIdx.x + 256 * i];
    ss += v[i] * v[i];
  }
  __shared__ float wsum[4];
  int lane = threadIdx.x & 63, wid = threadIdx.x >> 6;
#pragma unroll
  for (int off = 1; off < 64; off <<= 1) ss += __shfl_xor(ss, off);
  if (lane == 0) wsum[wid] = ss;
  __syncthreads();
  float tot = wsum[0] + wsum[1] + wsum[2] + wsum[3];
  float scale = rsqrtf(tot / (float)DMODEL + 1e-5f);
#pragma unroll
  for (int i = 0; i < 4; i++) {
    int j = threadIdx.x + 256 * i;
    xn[(size_t)row * DMODEL + j] = f2bf(v[i] * scale * w[j]);
  }
}

// ---------------- W [K][N] fp32 → W^T [N][K] bf16 (LDS-tiled) ----------------
__global__ __launch_bounds__(256) void transpose_w(
    const float* __restrict__ W, ushort* __restrict__ Wt, int K, int N) {
  __shared__ float tile[64][65];
  int n0 = blockIdx.x * 64, k0 = blockIdx.y * 64;
  int c = threadIdx.x & 63, rb = (threadIdx.x >> 6) << 4;
#pragma unroll
  for (int i = 0; i < 16; i++) {
    int k = k0 + rb + i;
    if (k < K && n0 + c < N) tile[rb + i][c] = W[(size_t)k * N + n0 + c];
  }
  __syncthreads();
#pragma unroll
  for (int i = 0; i < 16; i++) {
    int n = n0 + rb + i;
    if (n < N && k0 + c < K)
      Wt[(size_t)n * K + k0 + c] = f2bf(tile[c][rb + i]);
  }
}

// ---------------- bf16 MFMA GEMM: C[2048,N] = A[2048,K] @ Bt[N,K]^T ----------------
// 128x128 tile, BK=32, 4 waves, each wave 64x64 (4x4 of 16x16x32 mfma).
// mode 0: C0=fp32 out (+addend, ldc=N)
// mode 1: n<2048 -> C0=bf16 xsraw; n>=2048 -> C1=bf16 silu() gate   (N=4096)
// mode 2: C0=bf16 ssm (ld NSSM); n>=2048 -> C1=fp32 bc[m][n-2048] (ld 32)
// mode 3: C0=fp32 softplus()  (ld DINNER)
__global__ __launch_bounds__(256) void gemm_mfma(
    const ushort* __restrict__ A, int lda,
    const ushort* __restrict__ Bt, int ldb,
    int N, int K, int mode,
    void* __restrict__ C0, void* __restrict__ C1,
    const float* __restrict__ addend) {
  __shared__ ushort As[128][32];  // 8 KB, [m][k]
  __shared__ ushort Bs[128][32];  // 8 KB, [n][k]
  const int bm = blockIdx.y * 128, bn = blockIdx.x * 128;
  const int tid = threadIdx.x;
  const int wave = tid >> 6, lane = tid & 63;
  const int srow = tid >> 2;        // 0..63
  const int scol = (tid & 3) << 3;  // 0,8,16,24
  const int wm = (wave & 1) << 6, wn = (wave >> 1) << 6;
  const int lrow = lane & 15, quad = lane >> 4;

  const int brow0 = min(bn + srow, N - 1);        // clamp OOB rows (tail tile)
  const int brow1 = min(bn + srow + 64, N - 1);
  const ushort* ga0 = A + (size_t)(bm + srow) * lda + scol;
  const ushort* ga1 = A + (size_t)(bm + srow + 64) * lda + scol;
  const ushort* gb0 = Bt + (size_t)brow0 * ldb + scol;
  const ushort* gb1 = Bt + (size_t)brow1 * ldb + scol;

  floatx4 acc[4][4];
#pragma unroll
  for (int i = 0; i < 4; i++)
#pragma unroll
    for (int j = 0; j < 4; j++) acc[i][j] = (floatx4){0.f, 0.f, 0.f, 0.f};

  ushort8 ar0 = *(const ushort8*)ga0, ar1 = *(const ushort8*)ga1;
  ushort8 br0 = *(const ushort8*)gb0, br1 = *(const ushort8*)gb1;
  const int nk = K >> 5;
  for (int kt = 0; kt < nk; kt++) {
    __syncthreads();
    *(ushort8*)&As[srow][scol] = ar0;
    *(ushort8*)&As[srow + 64][scol] = ar1;
    *(ushort8*)&Bs[srow][scol] = br0;
    *(ushort8*)&Bs[srow + 64][scol] = br1;
    __syncthreads();
    if (kt + 1 < nk) {  // register prefetch of next tile overlaps MFMA below
      int off = (kt + 1) << 5;
      ar0 = *(const ushort8*)(ga0 + off);
      ar1 = *(const ushort8*)(ga1 + off);
      br0 = *(const ushort8*)(gb0 + off);
      br1 = *(const ushort8*)(gb1 + off);
    }
    bf16x8 af[4], bfr[4];
#pragma unroll
    for (int i = 0; i < 4; i++)
      af[i] = __builtin_bit_cast(bf16x8,
          *(const ushort8*)&As[wm + i * 16 + lrow][quad << 3]);
#pragma unroll
    for (int j = 0; j < 4; j++)
      bfr[j] = __builtin_bit_cast(bf16x8,
          *(const ushort8*)&Bs[wn + j * 16 + lrow][quad << 3]);
#pragma unroll
    for (int i = 0; i < 4; i++)
#pragma unroll
      for (int j = 0; j < 4; j++)
        acc[i][j] = __builtin_amdgcn_mfma_f32_16x16x32_bf16(
            af[i], bfr[j], acc[i][j], 0, 0, 0);
  }
  // epilogue: D row = quad*4+r, col = lane&15  [m89-verified]
  const int m0 = bm + wm, n0 = bn + wn, rq = quad << 2;
#pragma unroll
  for (int i = 0; i < 4; i++) {
#pragma unroll
    for (int j = 0; j < 4; j++) {
#pragma unroll
      for (int r = 0; r < 4; r++) {
        int m = m0 + i * 16 + rq + r;
        int n = n0 + j * 16 + lrow;
        if (n >= N) continue;
        float v = acc[i][j][r];
        if (mode == 0) {
          ((float*)C0)[(size_t)m * N + n] = v + addend[(size_t)m * N + n];
        } else if (mode == 1) {
          if (n < DINNER)
            ((ushort*)C0)[(size_t)m * DINNER + n] = f2bf(v);
          else
            ((ushort*)C1)[(size_t)m * DINNER + n - DINNER] = f2bf(silu_f(v));
        } else if (mode == 2) {
          ((ushort*)C0)[(size_t)m * NSSM + n] = f2bf(v);
          if (n >= DINNER)
            ((float*)C1)[(size_t)m * 32 + n - DINNER] = v;
        } else {
          ((float*)C0)[(size_t)m * DINNER + n] = softplus_f(v);
        }
      }
    }
  }
}

// ---------------- causal depthwise conv(4) + bias + silu (bf16 in/out) ----------------
__global__ __launch_bounds__(256) void conv_silu_kernel(
    const ushort* __restrict__ xsraw, const float* __restrict__ cw,
    const float* __restrict__ cb, ushort* __restrict__ xs) {
  int gid = blockIdx.x * 256 + threadIdx.x;
  int c = gid & (DINNER - 1);
  int t = gid >> 11;
  int l = t & (LSEQ - 1);
  float w0 = cw[c * 4 + 0], w1 = cw[c * 4 + 1], w2 = cw[c * 4 + 2], w3 = cw[c * 4 + 3];
  const ushort* col = xsraw + (size_t)t * DINNER + c;
  float acc = cb[c] + w3 * bf2f(col[0]);
  if (l >= 1) acc += w2 * bf2f(col[-DINNER]);
  if (l >= 2) acc += w1 * bf2f(col[-2 * DINNER]);
  if (l >= 3) acc += w0 * bf2f(col[-3 * DINNER]);
  xs[gid] = f2bf(silu_f(acc));
}

// ---------------- chunked selective scan (h[16]/thread, fp32 state) ----------------
__global__ __launch_bounds__(256) void scan_chunk1(
    const float* __restrict__ dt, const ushort* __restrict__ xs,
    const float* __restrict__ bc, const float* __restrict__ A_log,
    float* __restrict__ Bc, float* __restrict__ S) {
  int blk = blockIdx.x;
  int b = blk >> 8;
  int rem = blk & 255;
  int ch = rem >> 3;
  int dblk = rem & 7;
  int d = dblk * 256 + threadIdx.x;
  int c = b * DINNER + d;
  float a[DSTATE];
#pragma unroll
  for (int i = 0; i < 4; i++) {
    float4 v = *(const float4*)(A_log + (size_t)d * DSTATE + 4 * i);
    a[4 * i + 0] = -__expf(v.x);
    a[4 * i + 1] = -__expf(v.y);
    a[4 * i + 2] = -__expf(v.z);
    a[4 * i + 3] = -__expf(v.w);
  }
  float h[DSTATE] = {};
  float Ssum = 0.f;
  size_t t = (size_t)b * LSEQ + (size_t)ch * CL;
#pragma unroll 2
  for (int l = 0; l < CL; l++, t++) {
    float dtv = dt[t * DINNER + d];
    float dx = dtv * bf2f(xs[t * DINNER + d]);
    const float4* Bp = (const float4*)(bc + t * 32);
    float4 b0 = Bp[0], b1 = Bp[1], b2 = Bp[2], b3 = Bp[3];
    float bb[DSTATE] = {b0.x, b0.y, b0.z, b0.w, b1.x, b1.y, b1.z, b1.w,
                        b2.x, b2.y, b2.z, b2.w, b3.x, b3.y, b3.z, b3.w};
#pragma unroll
    for (int n = 0; n < DSTATE; n++)
      h[n] = __expf(a[n] * dtv) * h[n] + dx * bb[n];
    Ssum += dtv;
  }
  float4* outp = (float4*)(Bc + ((size_t)c * NCH + ch) * DSTATE);
  outp[0] = make_float4(h[0], h[1], h[2], h[3]);
  outp[1] = make_float4(h[4], h[5], h[6], h[7]);
  outp[2] = make_float4(h[8], h[9], h[10], h[11]);
  outp[3] = make_float4(h[12], h[13], h[14], h[15]);
  S[c * NCH + ch] = Ssum;
}

__global__ __launch_bounds__(256) void scan_combine(
    const float* __restrict__ A_log, const float* __restrict__ S,
    float* BcHin) {
  int gid = blockIdx.x * 256 + threadIdx.x;
  int c = gid >> 4, n = gid & 15;
  int d = c & (DINNER - 1);
  float a = -__expf(A_log[d * DSTATE + n]);
  float h = 0.f;
  size_t base = (size_t)c * (NCH * DSTATE) + n;
  for (int ch = 0; ch < NCH; ch++) {
    float bcv = BcHin[base + (size_t)ch * DSTATE];
    float decay = __expf(a * S[c * NCH + ch]);
    BcHin[base + (size_t)ch * DSTATE] = h;
    h = decay * h + bcv;
  }
}

__global__ __launch_bounds__(256) void scan_chunk2(
    const float* __restrict__ dt, const ushort* __restrict__ xs,
    const float* __restrict__ bc, const ushort* __restrict__ gate,
    const float* __restrict__ A_log, const float* __restrict__ hin,
    ushort* __restrict__ y) {
  int blk = blockIdx.x;
  int b = blk >> 8;
  int rem = blk & 255;
  int ch = rem >> 3;
  int dblk = rem & 7;
  int d = dblk * 256 + threadIdx.x;
  int c = b * DINNER + d;
  float a[DSTATE];
#pragma unroll
  for (int i = 0; i < 4; i++) {
    float4 v = *(const float4*)(A_log + (size_t)d * DSTATE + 4 * i);
    a[4 * i + 0] = -__expf(v.x);
    a[4 * i + 1] = -__expf(v.y);
    a[4 * i + 2] = -__expf(v.z);
    a[4 * i + 3] = -__expf(v.w);
  }
  float h[DSTATE];
  const float4* hi = (const float4*)(hin + ((size_t)c * NCH + ch) * DSTATE);
#pragma unroll
  for (int i = 0; i < 4; i++) {
    float4 v = hi[i];
    h[4 * i + 0] = v.x; h[4 * i + 1] = v.y; h[4 * i + 2] = v.z; h[4 * i + 3] = v.w;
  }
  size_t t = (size_t)b * LSEQ + (size_t)ch * CL;
#pragma unroll 2
  for (int l = 0; l < CL; l++, t++) {
    float dtv = dt[t * DINNER + d];
    float dx = dtv * bf2f(xs[t * DINNER + d]);
    const float4* Bp = (const float4*)(bc + t * 32);
    const float4* Cp = (const float4*)(bc + t * 32 + 16);
    float4 b0 = Bp[0], b1 = Bp[1], b2 = Bp[2], b3 = Bp[3];
    float4 c0 = Cp[0], c1 = Cp[1], c2 = Cp[2], c3 = Cp[3];
    float bb[DSTATE] = {b0.x, b0.y, b0.z, b0.w, b1.x, b1.y, b1.z, b1.w,
                        b2.x, b2.y, b2.z, b2.w, b3.x, b3.y, b3.z, b3.w};
    float cc[DSTATE] = {c0.x, c0.y, c0.z, c0.w, c1.x, c1.y, c1.z, c1.w,
                        c2.x, c2.y, c2.z, c2.w, c3.x, c3.y, c3.z, c3.w};
    float ysum = 0.f;
#pragma unroll
    for (int n = 0; n < DSTATE; n++) {
      h[n] = __expf(a[n] * dtv) * h[n] + dx * bb[n];
      ysum = fmaf(h[n], cc[n], ysum);
    }
    y[t * DINNER + d] = f2bf(ysum * bf2f(gate[t * DINNER + d]));
  }
}

extern "C" void kernel_launch(void* const* d_in, const int* in_sizes, int n_in,
                              void* d_out, int out_size, void* d_ws, size_t ws_size,
                              hipStream_t stream) {
  const float* x      = (const float*)d_in[0];
  const float* rms_w  = (const float*)d_in[1];
  const float* W_in   = (const float*)d_in[2];
  const float* conv_w = (const float*)d_in[3];
  const float* conv_b = (const float*)d_in[4];
  const float* W_x    = (const float*)d_in[5];
  const float* W_dt   = (const float*)d_in[6];
  const float* A_log  = (const float*)d_in[7];
  const float* W_out  = (const float*)d_in[8];
  float* out = (float*)d_out;

  // workspace layout, byte offsets (total 92,536,832 B = same as R1 footprint)
  char* w = (char*)d_ws;
  ushort* xnb   = (ushort*)(w + 0);         //  4 MiB  [2048,1024] bf16 (dead after GEMM1)
  ushort* xsraw = (ushort*)(w + 4194304);   //  8 MiB  [2048,2048] bf16 (dead after conv)
  ushort* gate  = (ushort*)(w + 12582912);  //  8 MiB  silu(res) bf16
  ushort* xsb   = (ushort*)(w + 20971520);  //  8 MiB  conv+silu out bf16
  ushort* ssmb  = (ushort*)(w + 29360128);  //  8.125 MiB [2048,2080] bf16
  float*  dtb   = (float*)(w + 37879808);   // 16 MiB  softplus(dt) fp32
  ushort* yb    = (ushort*)(w + 54657024);  //  8 MiB  scan out bf16
  ushort* WinT  = (ushort*)(w + 63045632);  //  8 MiB  [4096,1024]
  ushort* WxT   = (ushort*)(w + 71434240);  //  8.125 MiB [2080,2048]
  ushort* WdtT  = (ushort*)(w + 79953920);  //  8 MiB  [2048,2048]
  ushort* WoutT = (ushort*)(w + 88342528);  //  4 MiB  [1024,2048]
  // overlays of dead regions:
  float* bc = (float*)(w + 0);        // [2048,32] fp32 B|C (over xnb, 256 KiB) - written by GEMM2
  float* S  = (float*)(w + 262144);   // [NC,NCH] fp32 (over xnb, 512 KiB)
  float* Bc = (float*)(w + 4194304);  // [NC,NCH,16] fp32 (over xsraw, 8 MiB exactly)

  transpose_w<<<dim3(64, 16), 256, 0, stream>>>(W_in, WinT, DMODEL, 4096);
  transpose_w<<<dim3(33, 32), 256, 0, stream>>>(W_x, WxT, DINNER, NSSM);
  transpose_w<<<dim3(32, 32), 256, 0, stream>>>(W_dt, WdtT, DINNER, DINNER);
  transpose_w<<<dim3(16, 32), 256, 0, stream>>>(W_out, WoutT, DINNER, DMODEL);

  rmsnorm_kernel<<<NTOK, 256, 0, stream>>>(x, rms_w, xnb);
  // xr = xn @ W_in : split -> xsraw (bf16), gate = silu(res) (bf16)
  gemm_mfma<<<dim3(32, 16), 256, 0, stream>>>(
      xnb, DMODEL, WinT, DMODEL, 4096, DMODEL, 1, xsraw, gate, nullptr);
  conv_silu_kernel<<<(NTOK * DINNER) / 256, 256, 0, stream>>>(xsraw, conv_w, conv_b, xsb);
  // ssm = xs @ W_x : bf16 full + fp32 B/C columns compact
  gemm_mfma<<<dim3(17, 16), 256, 0, stream>>>(
      xsb, DINNER, WxT, DINNER, NSSM, DINNER, 2, ssmb, bc, nullptr);
  // dt = softplus(ssm[:, :2048] @ W_dt) fp32
  gemm_mfma<<<dim3(16, 16), 256, 0, stream>>>(
      ssmb, NSSM, WdtT, DINNER, DINNER, DINNER, 3, dtb, nullptr, nullptr);
  // chunked scan
  scan_chunk1<<<B_SZ * NCH * 8, 256, 0, stream>>>(dtb, xsb, bc, A_log, Bc, S);
  scan_combine<<<(NC * DSTATE) / 256, 256, 0, stream>>>(A_log, S, Bc);
  scan_chunk2<<<B_SZ * NCH * 8, 256, 0, stream>>>(dtb, xsb, bc, gate, A_log, Bc, yb);
  // out = y @ W_out + x
  gemm_mfma<<<dim3(8, 16), 256, 0, stream>>>(
      yb, DINNER, WoutT, DINNER, DMODEL, DINNER, 0, out, nullptr, x);
}